// Round 9
// baseline (802.820 us; speedup 1.0000x reference)
//
#include <hip/hip_runtime.h>
#include <hip/hip_bf16.h>
#include <hip/hip_cooperative_groups.h>

namespace cg = cooperative_groups;

// GCN 2-layer: h1 = relu(GCNConv(x, W1, b1)); out = log_softmax(GCNConv(h1, W2, b2))
// GCNConv(h)[d] = dinv[d] * ( sum_{s->d} (h@W)[s]*dinv[s] + (h@W)[d]*dinv[d] ) + b
//
// Round-9: single cooperative mega-kernel. r8 residual analysis: ~50-70us of the
// 153us controllable time is inter-kernel launch/drain overhead across 9 dependent
// kernels. Phases (identical math to r8, validated): hist -> scan1 -> scan2 ->
// partition -> bucket CSR (+dinv) -> gemm1(bf16 out) -> gather1+gemm2 -> gather2+lsm,
// separated by grid.sync(). Dtypes hardcoded (fp32 in/out, int32 edges; validated r3-r8).

#define FEAT_IN 64
#define FEAT_H  32
#define FEAT_O  16

__device__ __forceinline__ float2 upk_bf2(unsigned w) {
    return make_float2(__uint_as_float(w << 16), __uint_as_float(w & 0xFFFF0000u));
}

__global__ __launch_bounds__(256, 4) void k_mega(
    const float* __restrict__ x, const int* __restrict__ ei,
    const float* __restrict__ W1, const float* __restrict__ b1,
    const float* __restrict__ W2, const float* __restrict__ b2,
    float4* __restrict__ out4,
    int* __restrict__ part, int* __restrict__ col,
    __hip_bfloat162* __restrict__ h1s2, __hip_bfloat162* __restrict__ h2s2,
    float* __restrict__ dinv, int* __restrict__ row_start,
    int* __restrict__ hist, int* __restrict__ base, int* __restrict__ bsum,
    int n, int e, int NBk, int hlen)
{
    cg::grid_group grid = cg::this_grid();
    __shared__ __align__(16) char smbuf[12608];
    const int t = threadIdx.x;
    const int g = blockIdx.x;
    const int NBg = gridDim.x;
    const int* src = ei;
    const int* dst = ei + e;
    const int ce = (e + NBg - 1) / NBg;
    const int nblk = (hlen + 1023) >> 10;

    // ---- Phase A: per-block bucket histogram (bucket = dst>>8) ----
    {
        int* lh = (int*)smbuf;  // NBk <= 512 ints
        for (int i = t; i < NBk; i += 256) lh[i] = 0;
        __syncthreads();
        int beg = g * ce, end = min(e, beg + ce);
        for (int i = beg + t; i < end; i += 256) atomicAdd(&lh[dst[i] >> 8], 1);
        __syncthreads();
        for (int i = t; i < NBk; i += 256) hist[(size_t)i * NBg + g] = lh[i];
    }
    grid.sync();
    // ---- Phase B1: block-local exclusive scan of hist (1024/block) ----
    if (g < nblk) {
        int* s = (int*)smbuf;
        int bi = g * 1024 + t * 4;
        int a0 = (bi + 0 < hlen) ? hist[bi + 0] : 0;
        int a1 = (bi + 1 < hlen) ? hist[bi + 1] : 0;
        int a2 = (bi + 2 < hlen) ? hist[bi + 2] : 0;
        int a3 = (bi + 3 < hlen) ? hist[bi + 3] : 0;
        int tsum = a0 + a1 + a2 + a3;
        s[t] = tsum;
        __syncthreads();
        for (int off = 1; off < 256; off <<= 1) {
            int xv = (t >= off) ? s[t - off] : 0;
            __syncthreads();
            s[t] += xv;
            __syncthreads();
        }
        int ex = s[t] - tsum;
        if (bi + 0 < hlen) base[bi + 0] = ex;
        if (bi + 1 < hlen) base[bi + 1] = ex + a0;
        if (bi + 2 < hlen) base[bi + 2] = ex + a0 + a1;
        if (bi + 3 < hlen) base[bi + 3] = ex + a0 + a1 + a2;
        if (t == 255) bsum[g] = s[255];
    }
    grid.sync();
    // ---- Phase B2: block 0 scans bsum[nblk] (nblk <= 1024) ----
    if (g == 0) {
        int* s = (int*)smbuf;
        int i0 = t * 4;
        int a0 = (i0 + 0 < nblk) ? bsum[i0 + 0] : 0;
        int a1 = (i0 + 1 < nblk) ? bsum[i0 + 1] : 0;
        int a2 = (i0 + 2 < nblk) ? bsum[i0 + 2] : 0;
        int a3 = (i0 + 3 < nblk) ? bsum[i0 + 3] : 0;
        int tsum = a0 + a1 + a2 + a3;
        s[t] = tsum;
        __syncthreads();
        for (int off = 1; off < 256; off <<= 1) {
            int xv = (t >= off) ? s[t - off] : 0;
            __syncthreads();
            s[t] += xv;
            __syncthreads();
        }
        int ex = s[t] - tsum;
        if (i0 + 0 < nblk) bsum[i0 + 0] = ex;
        if (i0 + 1 < nblk) bsum[i0 + 1] = ex + a0;
        if (i0 + 2 < nblk) bsum[i0 + 2] = ex + a0 + a1;
        if (i0 + 3 < nblk) bsum[i0 + 3] = ex + a0 + a1 + a2;
    }
    grid.sync();
    // ---- Phase C: partition edges into bucket-ordered part[] (packed src|dlow<<24) ----
    {
        int* cur = (int*)smbuf;
        for (int i = t; i < NBk; i += 256) {
            size_t idx = (size_t)i * NBg + g;
            cur[i] = base[idx] + bsum[idx >> 10];
        }
        __syncthreads();
        int beg = g * ce, end = min(e, beg + ce);
        for (int i = beg + t; i < end; i += 256) {
            int s_ = src[i], d_ = dst[i];
            int pos = atomicAdd(&cur[d_ >> 8], 1);
            part[pos] = s_ | ((d_ & 255) << 24);   // n < 2^24
        }
    }
    grid.sync();
    // ---- Phase D: per-bucket CSR: count -> scan -> row_start/dinv -> col scatter ----
    {
        for (int b = g; b < NBk; b += NBg) {
            int* cnt = (int*)smbuf;        // 256
            int* ssc = cnt + 256;          // 256
            int* cur = ssc + 256;          // 256
            size_t i0 = (size_t)b << 10;   // careful: stride is NBg, not 1024
            size_t ib = (size_t)b * NBg;
            size_t ie = (size_t)(b + 1) * NBg;
            int beg = base[ib] + bsum[ib >> 10];
            int end = (b == NBk - 1) ? e : (base[ie] + bsum[ie >> 10]);
            (void)i0;
            cnt[t] = 0;
            __syncthreads();
            for (int j = beg + t; j < end; j += 256)
                atomicAdd(&cnt[((unsigned)part[j]) >> 24], 1);
            __syncthreads();
            int v = cnt[t];
            ssc[t] = v;
            __syncthreads();
            for (int off = 1; off < 256; off <<= 1) {
                int xv = (t >= off) ? ssc[t - off] : 0;
                __syncthreads();
                ssc[t] += xv;
                __syncthreads();
            }
            int rs = beg + ssc[t] - v;     // absolute row start
            int node = (b << 8) + t;
            if (node < n) {
                row_start[node] = rs;
                dinv[node] = rsqrtf((float)v + 1.0f);  // +1 self-loop
            }
            if (b == NBk - 1 && t == 255) row_start[n] = e;
            cur[t] = rs;
            __syncthreads();
            for (int j = beg + t; j < end; j += 256) {
                int r = part[j];
                int dl = ((unsigned)r) >> 24;
                int pos = atomicAdd(&cur[dl], 1);
                col[pos] = r & 0x00FFFFFF;
            }
            __syncthreads();
        }
    }
    grid.sync();
    // ---- Phase E: gemm1: h1s(bf16) = (x @ W1) * dinv ----
    {
        float* sW = (float*)smbuf;       // 2048 floats
        float* sx = sW + 2048;           // 16*65 floats
        for (int i = t; i < FEAT_IN * FEAT_H; i += 256) sW[i] = W1[i];
        int ntiles = (n + 31) >> 5;
        for (int T = g; T < ntiles; T += NBg) {
#pragma unroll
            for (int half = 0; half < 2; ++half) {
                int nodeBase = (T << 5) + (half << 4);
                __syncthreads();
                {
                    int xn = t >> 4, c = t & 15;
                    int node = nodeBase + xn;
                    if (node < n) {
                        float4 v = ((const float4*)x)[(size_t)node * 16 + c];
                        sx[xn * 65 + c * 4 + 0] = v.x;
                        sx[xn * 65 + c * 4 + 1] = v.y;
                        sx[xn * 65 + c * 4 + 2] = v.z;
                        sx[xn * 65 + c * 4 + 3] = v.w;
                    }
                }
                __syncthreads();
                int nl = t >> 4, gg = t & 15;
                int node = nodeBase + nl;
                if (node < n) {
                    float a0 = 0.0f, a1 = 0.0f;
#pragma unroll
                    for (int k = 0; k < FEAT_IN; ++k) {
                        float s = sx[nl * 65 + k];
                        a0 += s * sW[k * FEAT_H + 2 * gg];
                        a1 += s * sW[k * FEAT_H + 2 * gg + 1];
                    }
                    float dv = dinv[node];
                    __hip_bfloat162 o;
                    o.x = __float2bfloat16(a0 * dv);
                    o.y = __float2bfloat16(a1 * dv);
                    h1s2[(size_t)node * 16 + gg] = o;
                }
            }
        }
    }
    grid.sync();
    // ---- Phase G: gather layer1 (+relu+bias) + GEMM2 -> h2s(bf16); 64 nodes x 4 lanes ----
    {
        float* sW = (float*)smbuf;       // 512
        float* sb = sW + 512;            // 32
        float* sz = sb + 32;             // 64*33
        for (int i = t; i < FEAT_H * FEAT_O; i += 256) sW[i] = W2[i];
        if (t < FEAT_H) sb[t] = b1[t];
        const uint4* h1q = (const uint4*)h1s2;
        int ngr = (n + 63) >> 6;
        for (int q = g; q < ngr; q += NBg) {
            __syncthreads();
            int gg = t >> 2, l = t & 3;
            int d = (q << 6) + gg;
            if (d < n) {
                float a[8];
                {
                    uint4 u = h1q[(size_t)d * 4 + l];  // self-loop term
                    float2 p;
                    p = upk_bf2(u.x); a[0] = p.x; a[1] = p.y;
                    p = upk_bf2(u.y); a[2] = p.x; a[3] = p.y;
                    p = upk_bf2(u.z); a[4] = p.x; a[5] = p.y;
                    p = upk_bf2(u.w); a[6] = p.x; a[7] = p.y;
                }
                int beg = row_start[d], end = row_start[d + 1];
                int j = beg;
                for (; j + 4 <= end; j += 4) {
                    int c0 = col[j + 0], c1 = col[j + 1], c2 = col[j + 2], c3 = col[j + 3];
                    uint4 u0 = h1q[(size_t)c0 * 4 + l];
                    uint4 u1 = h1q[(size_t)c1 * 4 + l];
                    uint4 u2 = h1q[(size_t)c2 * 4 + l];
                    uint4 u3 = h1q[(size_t)c3 * 4 + l];
                    float2 p;
                    p = upk_bf2(u0.x); a[0] += p.x; a[1] += p.y;
                    p = upk_bf2(u0.y); a[2] += p.x; a[3] += p.y;
                    p = upk_bf2(u0.z); a[4] += p.x; a[5] += p.y;
                    p = upk_bf2(u0.w); a[6] += p.x; a[7] += p.y;
                    p = upk_bf2(u1.x); a[0] += p.x; a[1] += p.y;
                    p = upk_bf2(u1.y); a[2] += p.x; a[3] += p.y;
                    p = upk_bf2(u1.z); a[4] += p.x; a[5] += p.y;
                    p = upk_bf2(u1.w); a[6] += p.x; a[7] += p.y;
                    p = upk_bf2(u2.x); a[0] += p.x; a[1] += p.y;
                    p = upk_bf2(u2.y); a[2] += p.x; a[3] += p.y;
                    p = upk_bf2(u2.z); a[4] += p.x; a[5] += p.y;
                    p = upk_bf2(u2.w); a[6] += p.x; a[7] += p.y;
                    p = upk_bf2(u3.x); a[0] += p.x; a[1] += p.y;
                    p = upk_bf2(u3.y); a[2] += p.x; a[3] += p.y;
                    p = upk_bf2(u3.z); a[4] += p.x; a[5] += p.y;
                    p = upk_bf2(u3.w); a[6] += p.x; a[7] += p.y;
                }
                for (; j < end; ++j) {
                    uint4 u = h1q[(size_t)col[j] * 4 + l];
                    float2 p;
                    p = upk_bf2(u.x); a[0] += p.x; a[1] += p.y;
                    p = upk_bf2(u.y); a[2] += p.x; a[3] += p.y;
                    p = upk_bf2(u.z); a[4] += p.x; a[5] += p.y;
                    p = upk_bf2(u.w); a[6] += p.x; a[7] += p.y;
                }
                float dv = dinv[d];
#pragma unroll
                for (int k = 0; k < 8; ++k)
                    sz[gg * 33 + l * 8 + k] = fmaxf(dv * a[k] + sb[l * 8 + k], 0.0f);
            }
            __syncthreads();
#pragma unroll
            for (int it = 0; it < 2; ++it) {
                int nl = (t >> 3) + (it << 5);
                int m = t & 7;
                int node = (q << 6) + nl;
                if (node < n) {
                    float a0 = 0.0f, a1 = 0.0f;
#pragma unroll
                    for (int f = 0; f < FEAT_H; ++f) {
                        float z = sz[nl * 33 + f];
                        a0 += z * sW[f * FEAT_O + 2 * m];
                        a1 += z * sW[f * FEAT_O + 2 * m + 1];
                    }
                    float dv = dinv[node];
                    __hip_bfloat162 o;
                    o.x = __float2bfloat16(a0 * dv);
                    o.y = __float2bfloat16(a1 * dv);
                    h2s2[(size_t)node * 8 + m] = o;
                }
            }
        }
    }
    grid.sync();
    // ---- Phase H: gather layer2 + bias + log_softmax -> out(fp32); 128 nodes x 2 lanes ----
    {
        float* sb2 = (float*)smbuf;
        if (t < FEAT_O) sb2[t] = b2[t];
        const uint4* h2q = (const uint4*)h2s2;
        int ngr = (n + 127) >> 7;
        for (int q = g; q < ngr; q += NBg) {
            __syncthreads();
            int gg = t >> 1, hh = t & 1;
            int d = (q << 7) + gg;
            if (d < n) {
                float a[8];
                {
                    uint4 u = h2q[(size_t)d * 2 + hh];  // self-loop term
                    float2 p;
                    p = upk_bf2(u.x); a[0] = p.x; a[1] = p.y;
                    p = upk_bf2(u.y); a[2] = p.x; a[3] = p.y;
                    p = upk_bf2(u.z); a[4] = p.x; a[5] = p.y;
                    p = upk_bf2(u.w); a[6] = p.x; a[7] = p.y;
                }
                int beg = row_start[d], end = row_start[d + 1];
                int j = beg;
                for (; j + 4 <= end; j += 4) {
                    int c0 = col[j + 0], c1 = col[j + 1], c2 = col[j + 2], c3 = col[j + 3];
                    uint4 u0 = h2q[(size_t)c0 * 2 + hh];
                    uint4 u1 = h2q[(size_t)c1 * 2 + hh];
                    uint4 u2 = h2q[(size_t)c2 * 2 + hh];
                    uint4 u3 = h2q[(size_t)c3 * 2 + hh];
                    float2 p;
                    p = upk_bf2(u0.x); a[0] += p.x; a[1] += p.y;
                    p = upk_bf2(u0.y); a[2] += p.x; a[3] += p.y;
                    p = upk_bf2(u0.z); a[4] += p.x; a[5] += p.y;
                    p = upk_bf2(u0.w); a[6] += p.x; a[7] += p.y;
                    p = upk_bf2(u1.x); a[0] += p.x; a[1] += p.y;
                    p = upk_bf2(u1.y); a[2] += p.x; a[3] += p.y;
                    p = upk_bf2(u1.z); a[4] += p.x; a[5] += p.y;
                    p = upk_bf2(u1.w); a[6] += p.x; a[7] += p.y;
                    p = upk_bf2(u2.x); a[0] += p.x; a[1] += p.y;
                    p = upk_bf2(u2.y); a[2] += p.x; a[3] += p.y;
                    p = upk_bf2(u2.z); a[4] += p.x; a[5] += p.y;
                    p = upk_bf2(u2.w); a[6] += p.x; a[7] += p.y;
                    p = upk_bf2(u3.x); a[0] += p.x; a[1] += p.y;
                    p = upk_bf2(u3.y); a[2] += p.x; a[3] += p.y;
                    p = upk_bf2(u3.z); a[4] += p.x; a[5] += p.y;
                    p = upk_bf2(u3.w); a[6] += p.x; a[7] += p.y;
                }
                for (; j < end; ++j) {
                    uint4 u = h2q[(size_t)col[j] * 2 + hh];
                    float2 p;
                    p = upk_bf2(u.x); a[0] += p.x; a[1] += p.y;
                    p = upk_bf2(u.y); a[2] += p.x; a[3] += p.y;
                    p = upk_bf2(u.z); a[4] += p.x; a[5] += p.y;
                    p = upk_bf2(u.w); a[6] += p.x; a[7] += p.y;
                }
                float dv = dinv[d];
                float v[8];
                float mx = -1e30f;
#pragma unroll
                for (int k = 0; k < 8; ++k) {
                    v[k] = dv * a[k] + sb2[hh * 8 + k];
                    mx = fmaxf(mx, v[k]);
                }
                mx = fmaxf(mx, __shfl_xor(mx, 1));   // partner lane = other half, same node
                float ssum = 0.0f;
#pragma unroll
                for (int k = 0; k < 8; ++k) ssum += __expf(v[k] - mx);
                ssum += __shfl_xor(ssum, 1);
                float lg = mx + logf(ssum);
                float4 o0 = { v[0] - lg, v[1] - lg, v[2] - lg, v[3] - lg };
                float4 o1 = { v[4] - lg, v[5] - lg, v[6] - lg, v[7] - lg };
                out4[(size_t)d * 4 + hh * 2 + 0] = o0;
                out4[(size_t)d * 4 + hh * 2 + 1] = o1;
            }
        }
    }
}

extern "C" void kernel_launch(void* const* d_in, const int* in_sizes, int n_in,
                              void* d_out, int out_size, void* d_ws, size_t ws_size,
                              hipStream_t stream) {
    const float* x  = (const float*)d_in[0];
    const int*   ei = (const int*)d_in[1];
    const float* W1 = (const float*)d_in[2];
    const float* b1 = (const float*)d_in[3];
    const float* W2 = (const float*)d_in[4];
    const float* b2 = (const float*)d_in[5];
    float4* out4 = (float4*)d_out;

    int n = in_sizes[0] / FEAT_IN;   // 100000
    int e = in_sizes[1] / 2;         // 1600000
    int NBk = (n + 255) >> 8;        // 391 buckets of 256 (<= 512)

    // pick a co-residency-safe cooperative grid (4 blocks/CU target via launch_bounds)
    int occ = 0;
    hipOccupancyMaxActiveBlocksPerMultiprocessor(&occ, k_mega, 256, 0);
    if (occ < 1) occ = 1;
    int NBg = occ * 256;             // 256 CUs on MI355X
    if (NBg > 1024) NBg = 1024;
    int hlen = NBk * NBg;

    // workspace layout (16B-aligned heads; no aliasing)
    char* w = (char*)d_ws;
    int* part = (int*)w;                          w += (size_t)e * 4;        // 6.4 MB
    int* col  = (int*)w;                          w += (size_t)e * 4;        // 6.4 MB
    __hip_bfloat162* h1s2 = (__hip_bfloat162*)w;  w += (size_t)n * 64;       // 6.4 MB
    __hip_bfloat162* h2s2 = (__hip_bfloat162*)w;  w += (size_t)n * 32;       // 3.2 MB
    float* dinv = (float*)w;                      w += (size_t)n * 4;
    int* row_start = (int*)w;                     w += (size_t)(n + 1) * 4;
    int* bsum = (int*)w;                          w += 1024 * 4;
    int* hist = (int*)w;                          w += (size_t)hlen * 4;
    int* base = (int*)w;                          w += (size_t)hlen * 4;
    // total ~27.5 MB << ws_size

    void* args[] = {
        (void*)&x, (void*)&ei, (void*)&W1, (void*)&b1, (void*)&W2, (void*)&b2,
        (void*)&out4, (void*)&part, (void*)&col, (void*)&h1s2, (void*)&h2s2,
        (void*)&dinv, (void*)&row_start, (void*)&hist, (void*)&base, (void*)&bsum,
        (void*)&n, (void*)&e, (void*)&NBk, (void*)&hlen
    };
    hipLaunchCooperativeKernel(k_mega, dim3(NBg), dim3(256), args, 0, stream);
}

// Round 10
// 184.167 us; speedup vs baseline: 4.3592x; 4.3592x over previous
//
#include <hip/hip_runtime.h>
#include <hip/hip_bf16.h>

// GCN 2-layer: h1 = relu(GCNConv(x, W1, b1)); out = log_softmax(GCNConv(h1, W2, b2))
// GCNConv(h)[d] = dinv[d] * ( sum_{s->d} (h@W)[s]*dinv[s] + (h@W)[d]*dinv[d] ) + b
//
// Round-10: revert to r8 structure (197.7us known-good). r9's cooperative
// mega-kernel regressed 4x: grid.sync() on 8-XCD gfx950 flushes non-coherent
// per-XCD L2s -> every phase restarts cold (FETCH 104MB, 98% stall). Stream
// kernel boundaries are cheaper than grid-wide sync here.
// Trims vs r8: k_detect dropped (fp32 in/out + int32 edges validated r3-r9),
// k_scan2 folded into partition/bucket_csr (LDS scan of <=98 block sums),
// PART_G 192->256.

#define FEAT_IN 64
#define FEAT_H  32
#define FEAT_O  16
#define MAXNB   512   // max buckets of 256 nodes (n <= 131072; n < 2^24 for packing)
#define PART_G  256   // histogram/partition blocks
#define MAXSNB  128   // max scan blocks for hlen = MAXNB*PART_G

__device__ __forceinline__ float2 upk_bf2(unsigned w) {
    return make_float2(__uint_as_float(w << 16), __uint_as_float(w & 0xFFFF0000u));
}

// ---- pass 1: per-block bucket histogram -> hist[b*G + g] ----
__global__ void k_hist(const int* __restrict__ dst, int e,
                       int* __restrict__ hist, int G, int NBk) {
    __shared__ int lh[MAXNB];
    int t = threadIdx.x, g = blockIdx.x;
    for (int i = t; i < NBk; i += 256) lh[i] = 0;
    __syncthreads();
    int chunk = (e + G - 1) / G;
    int beg = g * chunk, end = min(e, beg + chunk);
    for (int i = beg + t; i < end; i += 256) atomicAdd(&lh[dst[i] >> 8], 1);
    __syncthreads();
    for (int i = t; i < NBk; i += 256) hist[(size_t)i * G + g] = lh[i];
}

// ---- block-local exclusive scan (1024 items/block); bsum[b] = raw block sum ----
__global__ void k_scan1(const int* __restrict__ in, int* __restrict__ out,
                        int* __restrict__ bsum, int len) {
    __shared__ int s[256];
    int t = threadIdx.x;
    int base = blockIdx.x * 1024 + t * 4;
    int a0 = (base + 0) < len ? in[base + 0] : 0;
    int a1 = (base + 1) < len ? in[base + 1] : 0;
    int a2 = (base + 2) < len ? in[base + 2] : 0;
    int a3 = (base + 3) < len ? in[base + 3] : 0;
    int tsum = a0 + a1 + a2 + a3;
    s[t] = tsum;
    __syncthreads();
    for (int off = 1; off < 256; off <<= 1) {
        int x = (t >= off) ? s[t - off] : 0;
        __syncthreads();
        s[t] += x;
        __syncthreads();
    }
    int ex = s[t] - tsum;
    if (base + 0 < len) out[base + 0] = ex;
    if (base + 1 < len) out[base + 1] = ex + a0;
    if (base + 2 < len) out[base + 2] = ex + a0 + a1;
    if (base + 3 < len) out[base + 3] = ex + a0 + a1 + a2;
    if (t == 255) bsum[blockIdx.x] = s[255];
}

// helper run inside consumers: LDS-exclusive-scan of raw bsum[snb] into sps[]
__device__ __forceinline__ void scan_bsum(const int* __restrict__ bsum, int snb,
                                          int* __restrict__ sps, int t) {
    if (t < snb) sps[t] = bsum[t];
    __syncthreads();
    if (t == 0) {
        int acc = 0;
        for (int i = 0; i < snb; ++i) { int v = sps[i]; sps[i] = acc; acc += v; }
    }
    __syncthreads();
}

// ---- pass 2: scatter packed (src | dlow<<24) into bucket-ordered part[] ----
__global__ void k_partition(const int* __restrict__ src, const int* __restrict__ dst, int e,
                            const int* __restrict__ base, const int* __restrict__ bsum,
                            int snb, int* __restrict__ part, int G, int NBk) {
    __shared__ int cur[MAXNB];
    __shared__ int sps[MAXSNB];
    int t = threadIdx.x, g = blockIdx.x;
    scan_bsum(bsum, snb, sps, t);
    for (int i = t; i < NBk; i += 256) {
        size_t idx = (size_t)i * G + g;
        cur[i] = base[idx] + sps[idx >> 10];
    }
    __syncthreads();
    int chunk = (e + G - 1) / G;
    int beg = g * chunk, end = min(e, beg + chunk);
    for (int i = beg + t; i < end; i += 256) {
        int s_ = src[i], d_ = dst[i];
        int pos = atomicAdd(&cur[d_ >> 8], 1);
        part[pos] = s_ | ((d_ & 255) << 24);   // n < 2^24
    }
}

// ---- pass 3: per-bucket CSR: LDS count -> scan -> row_start/dinv -> col fill ----
__global__ void k_bucket_csr(const int* __restrict__ part, const int* __restrict__ base,
                             const int* __restrict__ bsum, int snb, int e, int G, int NBk,
                             int n, int* __restrict__ row_start, int* __restrict__ col,
                             float* __restrict__ dinv) {
    __shared__ int cnt[256], spre[256], cur[256], ssc[256];
    __shared__ int sps[MAXSNB];
    int t = threadIdx.x, b = blockIdx.x;
    scan_bsum(bsum, snb, sps, t);
    size_t ib = (size_t)b * G;
    size_t ie = (size_t)(b + 1) * G;
    int beg = base[ib] + sps[ib >> 10];
    int end = (b == NBk - 1) ? e : (base[ie] + sps[ie >> 10]);
    cnt[t] = 0; cur[t] = 0;
    __syncthreads();
    for (int j = beg + t; j < end; j += 256) atomicAdd(&cnt[((unsigned)part[j]) >> 24], 1);
    __syncthreads();
    int v = cnt[t];
    ssc[t] = v;
    __syncthreads();
    for (int off = 1; off < 256; off <<= 1) {
        int x = (t >= off) ? ssc[t - off] : 0;
        __syncthreads();
        ssc[t] += x;
        __syncthreads();
    }
    spre[t] = ssc[t] - v;  // exclusive prefix within bucket
    int node = b * 256 + t;
    if (node < n) {
        row_start[node] = beg + spre[t];
        dinv[node] = rsqrtf((float)v + 1.0f);  // +1 self-loop
    }
    if (b == NBk - 1 && t == 0) row_start[n] = e;
    __syncthreads();
    for (int j = beg + t; j < end; j += 256) {
        int r = part[j];
        int dl = ((unsigned)r) >> 24;
        int off = atomicAdd(&cur[dl], 1);
        col[beg + spre[dl] + off] = r & 0x00FFFFFF;
    }
}

// ---- layer 1 GEMM: h1s(bf16) = (x @ W1) * dinv ; 32 nodes/block ----
__global__ void k_gemm1(const float* __restrict__ x, const float* __restrict__ W1,
                        const float* __restrict__ dinv,
                        __hip_bfloat162* __restrict__ h1s2, int n) {
    __shared__ float sW[FEAT_IN * FEAT_H];   // 8 KB
    __shared__ float sx[16][FEAT_IN + 1];
    int t = threadIdx.x;
    for (int i = t; i < FEAT_IN * FEAT_H; i += 256) sW[i] = W1[i];
#pragma unroll
    for (int tile = 0; tile < 2; ++tile) {
        int nodeBase = blockIdx.x * 32 + tile * 16;
        __syncthreads();
        {   // stage 16 nodes of x
            int xn = t >> 4, c = t & 15;
            int node = nodeBase + xn;
            if (node < n) {
                float4 v = ((const float4*)x)[(size_t)node * 16 + c];
                sx[xn][c * 4 + 0] = v.x; sx[xn][c * 4 + 1] = v.y;
                sx[xn][c * 4 + 2] = v.z; sx[xn][c * 4 + 3] = v.w;
            }
        }
        __syncthreads();
        int nl = t >> 4, g = t & 15;
        int node = nodeBase + nl;
        if (node < n) {
            float a0 = 0.0f, a1 = 0.0f;
#pragma unroll
            for (int k = 0; k < FEAT_IN; ++k) {
                float s = sx[nl][k];
                a0 += s * sW[k * FEAT_H + 2 * g];
                a1 += s * sW[k * FEAT_H + 2 * g + 1];
            }
            float dv = dinv[node];
            __hip_bfloat162 o;
            o.x = __float2bfloat16(a0 * dv);
            o.y = __float2bfloat16(a1 * dv);
            h1s2[(size_t)node * 16 + g] = o;
        }
    }
}

// ---- gather layer1 (+relu+bias) fused with GEMM2: 64 nodes x 4 lanes ----
__global__ void k_gather1_gemm2(const int* __restrict__ row_start, const int* __restrict__ col,
                                const uint4* __restrict__ h1q, const float* __restrict__ W2,
                                const float* __restrict__ b1,
                                const float* __restrict__ dinv,
                                __hip_bfloat162* __restrict__ h2s2, int n) {
    __shared__ float sW[FEAT_H * FEAT_O];
    __shared__ float sb1[FEAT_H];
    __shared__ float sz[64][FEAT_H + 1];
    int t = threadIdx.x;
    for (int i = t; i < FEAT_H * FEAT_O; i += 256) sW[i] = W2[i];
    if (t < FEAT_H) sb1[t] = b1[t];
    __syncthreads();

    int g = t >> 2, l = t & 3;          // 64 nodes, 4 lanes each (16B bf16 = 8 feats)
    int d = blockIdx.x * 64 + g;
    if (d < n) {
        float a[8];
        {   // self-loop term
            uint4 u = h1q[(size_t)d * 4 + l];
            float2 p;
            p = upk_bf2(u.x); a[0] = p.x; a[1] = p.y;
            p = upk_bf2(u.y); a[2] = p.x; a[3] = p.y;
            p = upk_bf2(u.z); a[4] = p.x; a[5] = p.y;
            p = upk_bf2(u.w); a[6] = p.x; a[7] = p.y;
        }
        int beg = row_start[d], end = row_start[d + 1];
        int j = beg;
        for (; j + 4 <= end; j += 4) {   // 4 independent 16B gathers in flight
            int c0 = col[j + 0], c1 = col[j + 1], c2 = col[j + 2], c3 = col[j + 3];
            uint4 u0 = h1q[(size_t)c0 * 4 + l];
            uint4 u1 = h1q[(size_t)c1 * 4 + l];
            uint4 u2 = h1q[(size_t)c2 * 4 + l];
            uint4 u3 = h1q[(size_t)c3 * 4 + l];
            float2 p;
            p = upk_bf2(u0.x); a[0] += p.x; a[1] += p.y;
            p = upk_bf2(u0.y); a[2] += p.x; a[3] += p.y;
            p = upk_bf2(u0.z); a[4] += p.x; a[5] += p.y;
            p = upk_bf2(u0.w); a[6] += p.x; a[7] += p.y;
            p = upk_bf2(u1.x); a[0] += p.x; a[1] += p.y;
            p = upk_bf2(u1.y); a[2] += p.x; a[3] += p.y;
            p = upk_bf2(u1.z); a[4] += p.x; a[5] += p.y;
            p = upk_bf2(u1.w); a[6] += p.x; a[7] += p.y;
            p = upk_bf2(u2.x); a[0] += p.x; a[1] += p.y;
            p = upk_bf2(u2.y); a[2] += p.x; a[3] += p.y;
            p = upk_bf2(u2.z); a[4] += p.x; a[5] += p.y;
            p = upk_bf2(u2.w); a[6] += p.x; a[7] += p.y;
            p = upk_bf2(u3.x); a[0] += p.x; a[1] += p.y;
            p = upk_bf2(u3.y); a[2] += p.x; a[3] += p.y;
            p = upk_bf2(u3.z); a[4] += p.x; a[5] += p.y;
            p = upk_bf2(u3.w); a[6] += p.x; a[7] += p.y;
        }
        for (; j < end; ++j) {
            uint4 u = h1q[(size_t)col[j] * 4 + l];
            float2 p;
            p = upk_bf2(u.x); a[0] += p.x; a[1] += p.y;
            p = upk_bf2(u.y); a[2] += p.x; a[3] += p.y;
            p = upk_bf2(u.z); a[4] += p.x; a[5] += p.y;
            p = upk_bf2(u.w); a[6] += p.x; a[7] += p.y;
        }
        float dv = dinv[d];
#pragma unroll
        for (int k = 0; k < 8; ++k)
            sz[g][l * 8 + k] = fmaxf(dv * a[k] + sb1[l * 8 + k], 0.0f);
    }
    __syncthreads();
    // GEMM2: 64 nodes x 8 output-pairs = 512 items / 256 thr = 2 iters; bf16 store
#pragma unroll
    for (int it = 0; it < 2; ++it) {
        int nl = (t >> 3) + it * 32;
        int m = t & 7;
        int node = blockIdx.x * 64 + nl;
        if (node < n) {
            float a0 = 0.0f, a1 = 0.0f;
#pragma unroll
            for (int f = 0; f < FEAT_H; ++f) {
                float z = sz[nl][f];
                a0 += z * sW[f * FEAT_O + 2 * m];
                a1 += z * sW[f * FEAT_O + 2 * m + 1];
            }
            float dv = dinv[node];
            __hip_bfloat162 o;
            o.x = __float2bfloat16(a0 * dv);
            o.y = __float2bfloat16(a1 * dv);
            h2s2[(size_t)node * 8 + m] = o;
        }
    }
}

// ---- gather layer2 + bias + log_softmax: 128 nodes x 2 lanes ----
__global__ void k_gather2_lsm(const int* __restrict__ row_start, const int* __restrict__ col,
                              const uint4* __restrict__ h2q, const float* __restrict__ b2,
                              const float* __restrict__ dinv,
                              float4* __restrict__ out4, int n) {
    __shared__ float sb2[FEAT_O];
    int t = threadIdx.x;
    if (t < FEAT_O) sb2[t] = b2[t];
    __syncthreads();
    int g = t >> 1, h = t & 1;          // 128 nodes, 2 lanes each (16B bf16 = 8 feats)
    int d = blockIdx.x * 128 + g;
    if (d >= n) return;
    float a[8];
    {
        uint4 u = h2q[(size_t)d * 2 + h];  // self-loop term
        float2 p;
        p = upk_bf2(u.x); a[0] = p.x; a[1] = p.y;
        p = upk_bf2(u.y); a[2] = p.x; a[3] = p.y;
        p = upk_bf2(u.z); a[4] = p.x; a[5] = p.y;
        p = upk_bf2(u.w); a[6] = p.x; a[7] = p.y;
    }
    int beg = row_start[d], end = row_start[d + 1];
    int j = beg;
    for (; j + 4 <= end; j += 4) {
        int c0 = col[j + 0], c1 = col[j + 1], c2 = col[j + 2], c3 = col[j + 3];
        uint4 u0 = h2q[(size_t)c0 * 2 + h];
        uint4 u1 = h2q[(size_t)c1 * 2 + h];
        uint4 u2 = h2q[(size_t)c2 * 2 + h];
        uint4 u3 = h2q[(size_t)c3 * 2 + h];
        float2 p;
        p = upk_bf2(u0.x); a[0] += p.x; a[1] += p.y;
        p = upk_bf2(u0.y); a[2] += p.x; a[3] += p.y;
        p = upk_bf2(u0.z); a[4] += p.x; a[5] += p.y;
        p = upk_bf2(u0.w); a[6] += p.x; a[7] += p.y;
        p = upk_bf2(u1.x); a[0] += p.x; a[1] += p.y;
        p = upk_bf2(u1.y); a[2] += p.x; a[3] += p.y;
        p = upk_bf2(u1.z); a[4] += p.x; a[5] += p.y;
        p = upk_bf2(u1.w); a[6] += p.x; a[7] += p.y;
        p = upk_bf2(u2.x); a[0] += p.x; a[1] += p.y;
        p = upk_bf2(u2.y); a[2] += p.x; a[3] += p.y;
        p = upk_bf2(u2.z); a[4] += p.x; a[5] += p.y;
        p = upk_bf2(u2.w); a[6] += p.x; a[7] += p.y;
        p = upk_bf2(u3.x); a[0] += p.x; a[1] += p.y;
        p = upk_bf2(u3.y); a[2] += p.x; a[3] += p.y;
        p = upk_bf2(u3.z); a[4] += p.x; a[5] += p.y;
        p = upk_bf2(u3.w); a[6] += p.x; a[7] += p.y;
    }
    for (; j < end; ++j) {
        uint4 u = h2q[(size_t)col[j] * 2 + h];
        float2 p;
        p = upk_bf2(u.x); a[0] += p.x; a[1] += p.y;
        p = upk_bf2(u.y); a[2] += p.x; a[3] += p.y;
        p = upk_bf2(u.z); a[4] += p.x; a[5] += p.y;
        p = upk_bf2(u.w); a[6] += p.x; a[7] += p.y;
    }
    float dv = dinv[d];
    float v[8];
    float mx = -1e30f;
#pragma unroll
    for (int k = 0; k < 8; ++k) {
        v[k] = dv * a[k] + sb2[h * 8 + k];
        mx = fmaxf(mx, v[k]);
    }
    mx = fmaxf(mx, __shfl_xor(mx, 1));   // partner lane = same node, other half
    float ssum = 0.0f;
#pragma unroll
    for (int k = 0; k < 8; ++k) ssum += __expf(v[k] - mx);
    ssum += __shfl_xor(ssum, 1);
    float lg = mx + logf(ssum);
    float4 o0 = { v[0] - lg, v[1] - lg, v[2] - lg, v[3] - lg };
    float4 o1 = { v[4] - lg, v[5] - lg, v[6] - lg, v[7] - lg };
    out4[(size_t)d * 4 + h * 2 + 0] = o0;
    out4[(size_t)d * 4 + h * 2 + 1] = o1;
}

extern "C" void kernel_launch(void* const* d_in, const int* in_sizes, int n_in,
                              void* d_out, int out_size, void* d_ws, size_t ws_size,
                              hipStream_t stream) {
    const float* x  = (const float*)d_in[0];
    const int*   ei = (const int*)d_in[1];
    const float* W1 = (const float*)d_in[2];
    const float* b1 = (const float*)d_in[3];
    const float* W2 = (const float*)d_in[4];
    const float* b2 = (const float*)d_in[5];

    const int n = in_sizes[0] / FEAT_IN;   // 100000
    const int e = in_sizes[1] / 2;         // 1600000
    const int* src = ei;
    const int* dst = ei + e;
    const int NBk = (n + 255) >> 8;        // 391 buckets of 256
    const int G = PART_G;                  // 256
    const int hlen = NBk * G;              // 100096
    const int snb = (hlen + 1023) / 1024;  // 98 (<= MAXSNB)

    // workspace; part (4B*e = 6.4MB) aliased with h1s bf16 (32n*2B = 6.4MB):
    // bucket_csr fully consumes part before k_gemm1 writes h1s (stream-ordered)
    int* part = (int*)d_ws;                                   // e ints
    __hip_bfloat162* h1s2 = (__hip_bfloat162*)d_ws;           // 16n bf162, same region
    int* col  = (int*)d_ws + e;                               // e ints
    __hip_bfloat162* h2s2 = (__hip_bfloat162*)(col + e);      // 8n bf162 (3.2MB)
    float* dinv = (float*)(h2s2 + 8 * (size_t)n);             // n
    int* hist      = (int*)(dinv + n);                        // hlen
    int* base      = hist + hlen;                             // hlen
    int* bsum      = base + hlen;                             // snb (raw block sums)
    int* row_start = bsum + MAXSNB;                           // n+1

    k_hist<<<G, 256, 0, stream>>>(dst, e, hist, G, NBk);
    k_scan1<<<snb, 256, 0, stream>>>(hist, base, bsum, hlen);
    k_partition<<<G, 256, 0, stream>>>(src, dst, e, base, bsum, snb, part, G, NBk);
    k_bucket_csr<<<NBk, 256, 0, stream>>>(part, base, bsum, snb, e, G, NBk, n,
                                          row_start, col, dinv);

    k_gemm1<<<(n + 31) / 32, 256, 0, stream>>>(x, W1, dinv, h1s2, n);
    k_gather1_gemm2<<<(n + 63) / 64, 256, 0, stream>>>(row_start, col, (const uint4*)h1s2,
                                                       W2, b1, dinv, h2s2, n);
    k_gather2_lsm<<<(n + 127) / 128, 256, 0, stream>>>(row_start, col, (const uint4*)h2s2,
                                                       b2, dinv, (float4*)d_out, n);
}